// Round 5
// baseline (1683.590 us; speedup 1.0000x reference)
//
#include <hip/hip_runtime.h>
#include <hip/hip_cooperative_groups.h>

namespace cg = cooperative_groups;

// out[n,:] = ci[n] * sum_{e: dst[e]==n} sigmoid(<review_feat[e,:], ps_w>) * cj[src[e]] * weight[src[e],:]
//
// Round-4 lesson: top-5 profile slots are all harness 3.2GB ws-poison fills;
// our 7 kernels are invisible and carry ~280us of unexplained overhead vs the
// ~260us model. Round 5: ONE cooperative kernel, grid.sync() between phases.
//   P1 zero deg | P2 histogram | P3 tile scans | P4 tile-total scan |
//   P5 globalize+cursor | P6 gate+CSR-scatter (819MB floor) | P7 gather
// 1024 blocks x 256 thr = 4 blocks/CU co-resident; single dispatch = full
// profile visibility. Fallback: round-4 multi-kernel path if coop launch fails.

#define NBLK 1024
#define NTHR 256
#define TILE_LOG 12
#define TILE (1 << TILE_LOG)

__global__ __launch_bounds__(NTHR, 4) void gcmc_fused(
    const float* __restrict__ weight,
    const float* __restrict__ ps_w,
    const float* __restrict__ review_feat,
    const float* __restrict__ cj,
    const float* __restrict__ ci,
    const int*   __restrict__ src,
    const int*   __restrict__ dst,
    float*       __restrict__ out,
    unsigned*    __restrict__ deg,      // [N]
    unsigned*    __restrict__ offs,     // [N+1]
    unsigned*    __restrict__ cursor,   // [N]
    unsigned*    __restrict__ tilesum,  // [ntiles]
    unsigned*    __restrict__ tileoff,  // [ntiles]
    int2*        __restrict__ pairs,    // [E] (src, scale-bits)
    int N, int E, int ntiles)
{
    cg::grid_group grid = cg::this_grid();

    const int t     = threadIdx.x;
    const int lane  = t & 63;
    const int wib   = t >> 6;
    const int group = lane >> 4;   // 4 work items per wave
    const int sub   = lane & 15;   // float4 chunk within a 64-row
    const long long gtid     = (long long)blockIdx.x * NTHR + t;
    const long long gthreads = (long long)NBLK * NTHR;
    const long long gwave    = (long long)blockIdx.x * (NTHR / 64) + wib;
    const long long gwaves   = (long long)NBLK * (NTHR / 64);

    __shared__ unsigned lds[TILE];   // 16KB
    __shared__ unsigned sums[NTHR];

    // ---- P1: zero deg ----
    for (long long i = gtid; i < N; i += gthreads) deg[i] = 0u;
    __threadfence();
    grid.sync();

    // ---- P2: degree histogram (device-scope atomics) ----
    for (long long e = gtid; e < E; e += gthreads) atomicAdd(&deg[dst[e]], 1u);
    __threadfence();
    grid.sync();

    // ---- P3: per-tile exclusive scan (coalesced) ----
    if ((int)blockIdx.x < ntiles) {
        const int base = (int)blockIdx.x << TILE_LOG;
        #pragma unroll
        for (int i = 0; i < TILE / NTHR; ++i) {
            const int idx = base + t + i * NTHR;
            lds[t + i * NTHR] = (idx < N) ? deg[idx] : 0u;     // coalesced
        }
        __syncthreads();
        const int C = TILE / NTHR;   // 16 elems per thread
        unsigned s = 0;
        #pragma unroll
        for (int i = 0; i < C; ++i) s += lds[C * t + i];
        sums[t] = s;
        __syncthreads();
        for (int off = 1; off < NTHR; off <<= 1) {             // Hillis-Steele
            const unsigned v = (t >= off) ? sums[t - off] : 0u;
            __syncthreads();
            sums[t] += v;
            __syncthreads();
        }
        unsigned run = sums[t] - s;                            // exclusive prefix
        #pragma unroll
        for (int i = 0; i < C; ++i) {
            const unsigned tmp = lds[C * t + i];
            lds[C * t + i] = run;
            run += tmp;
        }
        __syncthreads();
        #pragma unroll
        for (int i = 0; i < C; ++i) {
            const int idx = base + t + i * NTHR;
            if (idx < N) offs[idx] = lds[t + i * NTHR];        // coalesced
        }
        if (t == NTHR - 1) tilesum[blockIdx.x] = sums[NTHR - 1];
    }
    __threadfence();
    grid.sync();

    // ---- P4: scan tile totals (1 thread; ntiles ~ 25) ----
    if (blockIdx.x == 0 && t == 0) {
        unsigned run = 0;
        for (int b = 0; b < ntiles; ++b) { tileoff[b] = run; run += tilesum[b]; }
        offs[N] = run;   // == E
    }
    __threadfence();
    grid.sync();

    // ---- P5: globalize offsets, emit cursor ----
    for (long long i = gtid; i < N; i += gthreads) {
        const unsigned o = offs[i] + tileoff[i >> TILE_LOG];
        offs[i]   = o;
        cursor[i] = o;
    }
    __threadfence();
    grid.sync();

    // ---- P6: fused gate + CSR scatter ----
    {
        const float4 pw = *reinterpret_cast<const float4*>(ps_w + sub * 4);
        for (long long w = gwave; w * 4 < E; w += gwaves) {
            const long long e = w * 4 + group;
            float x = 0.f;
            if (e < E) {
                const float4 rv = *reinterpret_cast<const float4*>(review_feat + e * 64 + sub * 4);
                x = rv.x * pw.x + rv.y * pw.y + rv.z * pw.z + rv.w * pw.w;
            }
            x += __shfl_xor(x, 1);
            x += __shfl_xor(x, 2);
            x += __shfl_xor(x, 4);
            x += __shfl_xor(x, 8);
            if (sub == 0 && e < E) {
                const int s = src[e];
                const int d = dst[e];
                const float gate = 1.f / (1.f + __expf(-x));
                const float sc = gate * cj[s] * ci[d];   // ci[dst] folded in
                const unsigned pos = atomicAdd(&cursor[d], 1u);
                pairs[pos] = make_int2(s, __float_as_int(sc));
            }
        }
    }
    __threadfence();
    grid.sync();

    // ---- P7: gather-reduce, 4 nodes/wave, chunked coalesced pair loads ----
    for (long long q = gwave; q * 4 < N; q += gwaves) {
        const long long n = q * 4 + group;
        const bool valid = (n < N);
        unsigned start = 0, cnt = 0;
        if (valid) { start = offs[n]; cnt = offs[n + 1] - start; }

        float4 acc = make_float4(0.f, 0.f, 0.f, 0.f);
        for (unsigned k0 = 0; __any((int)(k0 < cnt)); k0 += 16) {
            int2 p = make_int2(0, 0);
            if (k0 + sub < cnt) p = pairs[start + k0 + sub];   // 128B/group coalesced
            int m = (int)cnt - (int)k0;
            if (m > 16) m = 16;
            for (int j = 0; j < m; ++j) {
                const int   s  = __shfl(p.x, (group << 4) + j);
                const float sc = __int_as_float(__shfl(p.y, (group << 4) + j));
                const float4 wv = *reinterpret_cast<const float4*>(
                    weight + (long long)s * 64 + sub * 4);     // 4 rows/wave-instr
                acc.x += sc * wv.x;
                acc.y += sc * wv.y;
                acc.z += sc * wv.z;
                acc.w += sc * wv.w;
            }
        }
        if (valid)
            *reinterpret_cast<float4*>(out + n * 64 + sub * 4) = acc;
    }
}

// ================= fallback: round-4 multi-kernel pipeline =================

__global__ __launch_bounds__(256) void kZ_zero(unsigned* __restrict__ p, int n)
{
    const int i = blockIdx.x * 256 + threadIdx.x;
    if (i < n) p[i] = 0u;
}

__global__ __launch_bounds__(256) void kA_hist(
    const int* __restrict__ dst, unsigned* __restrict__ deg, int E)
{
    const long long stride = (long long)gridDim.x * blockDim.x;
    for (long long e = (long long)blockIdx.x * blockDim.x + threadIdx.x; e < E; e += stride)
        atomicAdd(&deg[dst[e]], 1u);
}

__global__ __launch_bounds__(1024) void kB1_tile_scan(
    const unsigned* __restrict__ deg, unsigned* __restrict__ offs,
    unsigned* __restrict__ tilesum, int N)
{
    __shared__ unsigned lds[TILE];
    __shared__ unsigned sums[1024];
    const int t = threadIdx.x;
    const int base = blockIdx.x << TILE_LOG;
    #pragma unroll
    for (int i = 0; i < 4; ++i) {
        const int idx = base + t + i * 1024;
        lds[t + i * 1024] = (idx < N) ? deg[idx] : 0u;
    }
    __syncthreads();
    unsigned s = lds[4 * t] + lds[4 * t + 1] + lds[4 * t + 2] + lds[4 * t + 3];
    sums[t] = s;
    __syncthreads();
    for (int off = 1; off < 1024; off <<= 1) {
        const unsigned v = (t >= off) ? sums[t - off] : 0u;
        __syncthreads();
        sums[t] += v;
        __syncthreads();
    }
    unsigned run = sums[t] - s;
    #pragma unroll
    for (int i = 0; i < 4; ++i) {
        const unsigned tmp = lds[4 * t + i];
        lds[4 * t + i] = run;
        run += tmp;
    }
    __syncthreads();
    #pragma unroll
    for (int i = 0; i < 4; ++i) {
        const int idx = base + t + i * 1024;
        if (idx < N) offs[idx] = lds[t + i * 1024];
    }
    if (t == 1023) tilesum[blockIdx.x] = sums[1023];
}

__global__ void kB2_scan_tiles(
    const unsigned* __restrict__ tilesum, unsigned* __restrict__ tileoff,
    unsigned* __restrict__ offs, int ntiles, int N)
{
    if (threadIdx.x == 0 && blockIdx.x == 0) {
        unsigned run = 0;
        for (int b = 0; b < ntiles; ++b) { tileoff[b] = run; run += tilesum[b]; }
        offs[N] = run;
    }
}

__global__ __launch_bounds__(256) void kB3_add_offs(
    unsigned* __restrict__ offs, unsigned* __restrict__ cursor,
    const unsigned* __restrict__ tileoff, int N)
{
    const long long stride = (long long)gridDim.x * blockDim.x;
    for (long long i = (long long)blockIdx.x * blockDim.x + threadIdx.x; i < N; i += stride) {
        const unsigned o = offs[i] + tileoff[i >> TILE_LOG];
        offs[i] = o;
        cursor[i] = o;
    }
}

__global__ __launch_bounds__(256) void kC_gate_scatter(
    const float* __restrict__ review_feat, const float* __restrict__ ps_w,
    const float* __restrict__ cj, const float* __restrict__ ci,
    const int* __restrict__ src, const int* __restrict__ dst,
    unsigned* __restrict__ cursor, int2* __restrict__ pairs, int E)
{
    const int lane  = threadIdx.x & 63;
    const int wib   = threadIdx.x >> 6;
    const int group = lane >> 4;
    const int sub   = lane & 15;
    const float4 pw = *reinterpret_cast<const float4*>(ps_w + sub * 4);
    const long long nwaves = (long long)gridDim.x * 4;
    for (long long w = (long long)blockIdx.x * 4 + wib; w * 4 < E; w += nwaves) {
        const long long e = w * 4 + group;
        float x = 0.f;
        if (e < E) {
            const float4 rv = *reinterpret_cast<const float4*>(review_feat + e * 64 + sub * 4);
            x = rv.x * pw.x + rv.y * pw.y + rv.z * pw.z + rv.w * pw.w;
        }
        x += __shfl_xor(x, 1);
        x += __shfl_xor(x, 2);
        x += __shfl_xor(x, 4);
        x += __shfl_xor(x, 8);
        if (sub == 0 && e < E) {
            const int s = src[e];
            const int d = dst[e];
            const float gate = 1.f / (1.f + __expf(-x));
            const float sc = gate * cj[s] * ci[d];
            const unsigned pos = atomicAdd(&cursor[d], 1u);
            pairs[pos] = make_int2(s, __float_as_int(sc));
        }
    }
}

__global__ __launch_bounds__(256) void kD_gather(
    const float* __restrict__ weight, const unsigned* __restrict__ offs,
    const int2* __restrict__ pairs, float* __restrict__ out, int N)
{
    const int lane  = threadIdx.x & 63;
    const int wib   = threadIdx.x >> 6;
    const int group = lane >> 4;
    const int sub   = lane & 15;
    const long long n = ((long long)blockIdx.x * 4 + wib) * 4 + group;
    const bool valid = (n < N);
    unsigned start = 0, cnt = 0;
    if (valid) { start = offs[n]; cnt = offs[n + 1] - start; }
    float4 acc = make_float4(0.f, 0.f, 0.f, 0.f);
    for (unsigned k0 = 0; __any((int)(k0 < cnt)); k0 += 16) {
        int2 p = make_int2(0, 0);
        if (k0 + sub < cnt) p = pairs[start + k0 + sub];
        int m = (int)cnt - (int)k0;
        if (m > 16) m = 16;
        for (int j = 0; j < m; ++j) {
            const int   s  = __shfl(p.x, (group << 4) + j);
            const float sc = __int_as_float(__shfl(p.y, (group << 4) + j));
            const float4 w = *reinterpret_cast<const float4*>(
                weight + (long long)s * 64 + sub * 4);
            acc.x += sc * w.x;
            acc.y += sc * w.y;
            acc.z += sc * w.z;
            acc.w += sc * w.w;
        }
    }
    if (valid)
        *reinterpret_cast<float4*>(out + n * 64 + sub * 4) = acc;
}

extern "C" void kernel_launch(void* const* d_in, const int* in_sizes, int n_in,
                              void* d_out, int out_size, void* d_ws, size_t ws_size,
                              hipStream_t stream) {
    const float* weight      = (const float*)d_in[0];
    const float* ps_w        = (const float*)d_in[1];
    const float* review_feat = (const float*)d_in[2];
    const float* cj          = (const float*)d_in[3];
    const float* ci          = (const float*)d_in[4];
    const int*   src         = (const int*)d_in[5];
    const int*   dst         = (const int*)d_in[6];
    float*       out         = (float*)d_out;

    const int N = in_sizes[3];
    const int E = in_sizes[5];
    const int ntiles = (N + TILE - 1) / TILE;

    size_t off = 0;
    auto take = [&](size_t bytes) { size_t o = off; off = (off + bytes + 255) & ~(size_t)255; return o; };
    const size_t pairs_o   = take((size_t)E * 8);
    const size_t deg_o     = take((size_t)N * 4);
    const size_t offs_o    = take(((size_t)N + 1) * 4);
    const size_t cursor_o  = take((size_t)N * 4);
    const size_t tilesum_o = take((size_t)ntiles * 4);
    const size_t tileoff_o = take((size_t)ntiles * 4);

    char* base = (char*)d_ws;
    int2*     pairs   = (int2*)    (base + pairs_o);
    unsigned* deg     = (unsigned*)(base + deg_o);
    unsigned* offs    = (unsigned*)(base + offs_o);
    unsigned* cursor  = (unsigned*)(base + cursor_o);
    unsigned* tilesum = (unsigned*)(base + tilesum_o);
    unsigned* tileoff = (unsigned*)(base + tileoff_o);

    // ---- cooperative fused path ----
    int n_ = N, e_ = E, nt_ = ntiles;
    void* args[] = {
        (void*)&weight, (void*)&ps_w, (void*)&review_feat, (void*)&cj, (void*)&ci,
        (void*)&src, (void*)&dst, (void*)&out,
        (void*)&deg, (void*)&offs, (void*)&cursor, (void*)&tilesum, (void*)&tileoff,
        (void*)&pairs, (void*)&n_, (void*)&e_, (void*)&nt_
    };
    hipError_t err = hipLaunchCooperativeKernel(
        (const void*)gcmc_fused, dim3(NBLK), dim3(NTHR), args, 0, stream);

    if (err != hipSuccess) {
        // ---- fallback: round-4 multi-kernel pipeline ----
        kZ_zero<<<(N + 255) / 256, 256, 0, stream>>>(deg, N);
        kA_hist<<<1024, 256, 0, stream>>>(dst, deg, E);
        kB1_tile_scan<<<ntiles, 1024, 0, stream>>>(deg, offs, tilesum, N);
        kB2_scan_tiles<<<1, 64, 0, stream>>>(tilesum, tileoff, offs, ntiles, N);
        kB3_add_offs<<<256, 256, 0, stream>>>(offs, cursor, tileoff, N);
        kC_gate_scatter<<<2048, 256, 0, stream>>>(review_feat, ps_w, cj, ci, src, dst,
                                                  cursor, pairs, E);
        const int blocksD = (N + 15) / 16;
        kD_gather<<<blocksD, 256, 0, stream>>>(weight, offs, pairs, out, N);
    }
}

// Round 6
// 546.906 us; speedup vs baseline: 3.0784x; 3.0784x over previous
//
#include <hip/hip_runtime.h>

// out[n,:] = ci[n] * sum_{e: dst[e]==n} sigmoid(<review_feat[e,:], ps_w>) * cj[src[e]] * weight[src[e],:]
//
// Round-5 lesson (fused coop kernel, full visibility): total traffic is only
// 1.18GB (~190us at stream BW) but VALUBusy=4.3%, VGPR=28 -> the pipeline is
// LATENCY-bound; wave count + in-flight loads are the levers. Round 6 reverts
// to the multi-kernel pipeline (best grid per phase) and rebuilds kD for MLP:
//   - prefetch next 16-pair chunk before processing current
//   - #pragma unroll 8 inner loop -> up to 8 outstanding float4 weight gathers
//   - __launch_bounds__(256,4): VGPR cap 128 (room for ILP), 16 waves/CU
// kC: src/dst loads hoisted ahead of the shfl butterfly to overlap latency.

#define TILE_LOG 12
#define TILE (1 << TILE_LOG)   // 4096 elems per scan tile

// ---------------- kZ: zero the degree array ----------------
__global__ __launch_bounds__(256) void kZ_zero(unsigned* __restrict__ p, int n)
{
    const int i = blockIdx.x * 256 + threadIdx.x;
    if (i < n) p[i] = 0u;
}

// ---------------- kA: degree histogram ----------------
__global__ __launch_bounds__(256) void kA_hist(
    const int* __restrict__ dst, unsigned* __restrict__ deg, int E)
{
    const long long stride = (long long)gridDim.x * blockDim.x;
    for (long long e = (long long)blockIdx.x * blockDim.x + threadIdx.x; e < E; e += stride)
        atomicAdd(&deg[dst[e]], 1u);
}

// ---------------- kB1: per-tile exclusive scan (coalesced) ----------------
__global__ __launch_bounds__(1024) void kB1_tile_scan(
    const unsigned* __restrict__ deg, unsigned* __restrict__ offs,
    unsigned* __restrict__ tilesum, int N)
{
    __shared__ unsigned lds[TILE];
    __shared__ unsigned sums[1024];
    const int t = threadIdx.x;
    const int base = blockIdx.x << TILE_LOG;
    #pragma unroll
    for (int i = 0; i < 4; ++i) {
        const int idx = base + t + i * 1024;
        lds[t + i * 1024] = (idx < N) ? deg[idx] : 0u;   // coalesced
    }
    __syncthreads();
    unsigned s = lds[4 * t] + lds[4 * t + 1] + lds[4 * t + 2] + lds[4 * t + 3];
    sums[t] = s;
    __syncthreads();
    for (int off = 1; off < 1024; off <<= 1) {
        const unsigned v = (t >= off) ? sums[t - off] : 0u;
        __syncthreads();
        sums[t] += v;
        __syncthreads();
    }
    unsigned run = sums[t] - s;
    #pragma unroll
    for (int i = 0; i < 4; ++i) {
        const unsigned tmp = lds[4 * t + i];
        lds[4 * t + i] = run;
        run += tmp;
    }
    __syncthreads();
    #pragma unroll
    for (int i = 0; i < 4; ++i) {
        const int idx = base + t + i * 1024;
        if (idx < N) offs[idx] = lds[t + i * 1024];      // coalesced
    }
    if (t == 1023) tilesum[blockIdx.x] = sums[1023];
}

// ---------------- kB2: scan tile totals ----------------
__global__ void kB2_scan_tiles(
    const unsigned* __restrict__ tilesum, unsigned* __restrict__ tileoff,
    unsigned* __restrict__ offs, int ntiles, int N)
{
    if (threadIdx.x == 0 && blockIdx.x == 0) {
        unsigned run = 0;
        for (int b = 0; b < ntiles; ++b) { tileoff[b] = run; run += tilesum[b]; }
        offs[N] = run;   // == E
    }
}

// ---------------- kB3: globalize offsets, emit cursor ----------------
__global__ __launch_bounds__(256) void kB3_add_offs(
    unsigned* __restrict__ offs, unsigned* __restrict__ cursor,
    const unsigned* __restrict__ tileoff, int N)
{
    const long long stride = (long long)gridDim.x * blockDim.x;
    for (long long i = (long long)blockIdx.x * blockDim.x + threadIdx.x; i < N; i += stride) {
        const unsigned o = offs[i] + tileoff[i >> TILE_LOG];
        offs[i] = o;
        cursor[i] = o;
    }
}

// ---------------- kC: fused gate + CSR scatter ----------------
__global__ __launch_bounds__(256) void kC_gate_scatter(
    const float* __restrict__ review_feat, const float* __restrict__ ps_w,
    const float* __restrict__ cj, const float* __restrict__ ci,
    const int* __restrict__ src, const int* __restrict__ dst,
    unsigned* __restrict__ cursor, int2* __restrict__ pairs, int E)
{
    const int lane  = threadIdx.x & 63;
    const int wib   = threadIdx.x >> 6;
    const int group = lane >> 4;
    const int sub   = lane & 15;
    const float4 pw = *reinterpret_cast<const float4*>(ps_w + sub * 4);

    const long long nwaves = (long long)gridDim.x * 4;
    for (long long w = (long long)blockIdx.x * 4 + wib; w * 4 < E; w += nwaves) {
        const long long e = w * 4 + group;
        // hoist index loads so they're in flight during the dot+butterfly
        int s = 0, d = 0;
        if (sub == 0 && e < E) { s = src[e]; d = dst[e]; }

        float x = 0.f;
        if (e < E) {
            const float4 rv = *reinterpret_cast<const float4*>(review_feat + e * 64 + sub * 4);
            x = rv.x * pw.x + rv.y * pw.y + rv.z * pw.z + rv.w * pw.w;
        }
        x += __shfl_xor(x, 1);
        x += __shfl_xor(x, 2);
        x += __shfl_xor(x, 4);
        x += __shfl_xor(x, 8);

        if (sub == 0 && e < E) {
            const float gate = 1.f / (1.f + __expf(-x));
            const float sc = gate * cj[s] * ci[d];     // ci[dst] folded in
            const unsigned pos = atomicAdd(&cursor[d], 1u);
            pairs[pos] = make_int2(s, __float_as_int(sc));
        }
    }
}

// ---------------- kD: gather-reduce, ILP-restructured ----------------
// 4 nodes/wave, 16 lanes (float4) per node. Next pair chunk is prefetched
// before processing the current one; the j-loop is unrolled so multiple
// independent weight gathers are outstanding (VGPR cap 128 via bounds(256,4)).
__global__ __launch_bounds__(256, 4) void kD_gather(
    const float* __restrict__ weight, const unsigned* __restrict__ offs,
    const int2* __restrict__ pairs, float* __restrict__ out, int N)
{
    const int lane  = threadIdx.x & 63;
    const int wib   = threadIdx.x >> 6;
    const int group = lane >> 4;   // node within wave
    const int sub   = lane & 15;   // float4 chunk of the row

    const long long n = ((long long)blockIdx.x * 4 + wib) * 4 + group;
    const bool valid = (n < N);

    unsigned start = 0, cnt = 0;
    if (valid) { start = offs[n]; cnt = offs[n + 1] - start; }

    // prefetch chunk 0
    int2 p = make_int2(0, 0);
    if (sub < cnt) p = pairs[start + sub];

    float4 acc = make_float4(0.f, 0.f, 0.f, 0.f);
    for (unsigned k0 = 0; __any((int)(k0 < cnt)); k0 += 16) {
        // prefetch next chunk while we chew on this one
        int2 pn = make_int2(0, 0);
        const unsigned nk = k0 + 16;
        if (nk + sub < cnt) pn = pairs[start + nk + sub];

        int m = (int)cnt - (int)k0;          // group-uniform
        if (m > 16) m = 16;
        #pragma unroll 8
        for (int j = 0; j < m; ++j) {
            const int   s  = __shfl(p.x, (group << 4) + j);
            const float sc = __int_as_float(__shfl(p.y, (group << 4) + j));
            const float4 w = *reinterpret_cast<const float4*>(
                weight + (long long)s * 64 + sub * 4);   // 4 rows/wave-instr = 1KB
            acc.x += sc * w.x;
            acc.y += sc * w.y;
            acc.z += sc * w.z;
            acc.w += sc * w.w;
        }
        p = pn;
    }
    if (valid)
        *reinterpret_cast<float4*>(out + n * 64 + sub * 4) = acc;
}

extern "C" void kernel_launch(void* const* d_in, const int* in_sizes, int n_in,
                              void* d_out, int out_size, void* d_ws, size_t ws_size,
                              hipStream_t stream) {
    const float* weight      = (const float*)d_in[0];
    const float* ps_w        = (const float*)d_in[1];
    const float* review_feat = (const float*)d_in[2];
    const float* cj          = (const float*)d_in[3];
    const float* ci          = (const float*)d_in[4];
    const int*   src         = (const int*)d_in[5];
    const int*   dst         = (const int*)d_in[6];
    float*       out         = (float*)d_out;

    const int N = in_sizes[3];
    const int E = in_sizes[5];
    const int ntiles = (N + TILE - 1) / TILE;

    size_t off = 0;
    auto take = [&](size_t bytes) { size_t o = off; off = (off + bytes + 255) & ~(size_t)255; return o; };
    const size_t pairs_o   = take((size_t)E * 8);
    const size_t deg_o     = take((size_t)N * 4);
    const size_t offs_o    = take(((size_t)N + 1) * 4);
    const size_t cursor_o  = take((size_t)N * 4);
    const size_t tilesum_o = take((size_t)ntiles * 4);
    const size_t tileoff_o = take((size_t)ntiles * 4);

    char* base = (char*)d_ws;
    int2*     pairs   = (int2*)    (base + pairs_o);
    unsigned* deg     = (unsigned*)(base + deg_o);
    unsigned* offs    = (unsigned*)(base + offs_o);
    unsigned* cursor  = (unsigned*)(base + cursor_o);
    unsigned* tilesum = (unsigned*)(base + tilesum_o);
    unsigned* tileoff = (unsigned*)(base + tileoff_o);

    kZ_zero<<<(N + 255) / 256, 256, 0, stream>>>(deg, N);
    kA_hist<<<2048, 256, 0, stream>>>(dst, deg, E);
    kB1_tile_scan<<<ntiles, 1024, 0, stream>>>(deg, offs, tilesum, N);
    kB2_scan_tiles<<<1, 64, 0, stream>>>(tilesum, tileoff, offs, ntiles, N);
    kB3_add_offs<<<256, 256, 0, stream>>>(offs, cursor, tileoff, N);
    kC_gate_scatter<<<2048, 256, 0, stream>>>(review_feat, ps_w, cj, ci, src, dst,
                                              cursor, pairs, E);
    const int blocksD = (N + 15) / 16;   // 16 nodes per block (4 waves x 4 nodes)
    kD_gather<<<blocksD, 256, 0, stream>>>(weight, offs, pairs, out, N);
}